// Round 8
// baseline (93.052 us; speedup 1.0000x reference)
//
#include <hip/hip_runtime.h>

// Problem constants
#define BATCH 16
#define CIN   64
#define H_    64
#define W_    64
#define IMG   (H_ * W_)      // 4096
#define OCH   128
#define NLEAF 16
#define NGATE 15
#define PH    32
#define PW    32

// d_ws: coeffs = 128 ocs x 16 float4 (slot15 pad) = 8192 floats, then descs
#define C_STRIDE_F4 16
#define DESC_OFF    8192

// LDS: 2 guard zeros, then [64 ch][6 rows][66 cols] floats; cols 64,65 = 0.
// Row stride 66 makes col -1 of row r alias row r-1's zero pad -> both
// column halos are free; no masks/clamps/cndmask in the hot loop.
#define ROWS   6
#define RSTR   66
#define CHSTR  (ROWS * RSTR)        // 396
#define XSB    2
#define SMEM_F (XSB + CIN * CHSTR)  // 25346 floats = 101,384 B

typedef float f2 __attribute__((ext_vector_type(2)));

__device__ __constant__ __align__(16) float OP2POLY[16][4] = {
    {0, 0, 0, 0}, {0, 0, 0, 1}, {0, 1, 0, -1}, {0, 1, 0, 0},
    {0, 0, 1, -1}, {0, 0, 1, 0}, {0, 1, 1, -2}, {0, 1, 1, -1},
    {1, -1, -1, 1}, {1, -1, -1, 2}, {1, 0, -1, 0}, {1, 0, -1, 1},
    {1, -1, 0, 0}, {1, -1, 0, 1}, {1, 0, 0, -1}, {1, 0, 0, 0}};

// ---------------------------------------------------------------------------
// Prep: coeffs[oc][g] = OP2POLY[argmax(weights[oc][g][:])] (forward value of
// the straight-through w is exactly the one-hot argmax), and leaf descriptors
//   desc = XSB + ch*CHSTR + py*RSTR + px - 1   (wave-uniform; s_load in main)
// ---------------------------------------------------------------------------
__global__ __launch_bounds__(1024) void prep(
    const float* __restrict__ weights,  // (OC, 15, 16)
    const int* __restrict__ ci,         // (OC, 16)
    const int* __restrict__ px,         // (OC, 16)
    const int* __restrict__ py,         // (OC, 16)
    float* __restrict__ ws)
{
    int t = blockIdx.x * 1024 + threadIdx.x;
    if (t < OCH * NGATE) {
        const float4* wp4 = reinterpret_cast<const float4*>(weights + t * 16);
        const float4 a0 = wp4[0], a1 = wp4[1], a2 = wp4[2], a3 = wp4[3];
        const float wv[16] = {a0.x, a0.y, a0.z, a0.w, a1.x, a1.y, a1.z, a1.w,
                              a2.x, a2.y, a2.z, a2.w, a3.x, a3.y, a3.z, a3.w};
        int best = 0;
        float bv = wv[0];
#pragma unroll
        for (int k = 1; k < 16; ++k)
            if (wv[k] > bv) { bv = wv[k]; best = k; }   // first-max (jnp.argmax)
        int oc = t / 15, g = t - oc * 15;
        reinterpret_cast<float4*>(ws)[oc * C_STRIDE_F4 + g] =
            reinterpret_cast<const float4*>(OP2POLY)[best];
    } else if (t < OCH * NGATE + OCH * NLEAF) {
        int t2 = t - OCH * NGATE;
        ((int*)ws)[DESC_OFF + t2] =
            XSB + ci[t2] * CHSTR + py[t2] * RSTR + px[t2] - 1;
    }
}

// ---------------------------------------------------------------------------
// Main. Block = (b, strip of 4 pre-pool rows); 1024 threads = 16 waves;
// XCD swizzle (XCD x -> batches 2x,2x+1; 32 blocks/XCD = 1/CU). Phase 1:
// stage x rows r0-1..r0+4 (64 ch) into stride-66 LDS with zeroed pads (free
// halos). Phase 2: wave w -> ocs [8w,8w+8); lane = column. Per oc: descs via
// s_load, base = desc+lane, rows as two f2 pairs (ds_read2_b32 offsets
// 0/66 and 132/198), 15-gate tree in packed fp32 (v_pk_fma), 2x2 noisy-or
// pool, one all-lane store.
// ---------------------------------------------------------------------------
__global__ __launch_bounds__(1024, 4) void logic_tree_main(
    const float* __restrict__ x,        // (B, Cin, 64, 64)
    const float* __restrict__ ws,
    float* __restrict__ out)            // (B, OC, 32, 32)
{
    __shared__ float smem[SMEM_F];

    const int blk = blockIdx.x;
    const int xcd = blk & 7;
    const int j   = blk >> 3;
    const int b   = (xcd << 1) | (j >> 4);
    const int strip = j & 15;
    const int r0  = strip << 2;
    const int tid = threadIdx.x;

    // ---- stage interior (float2; 8B-aligned LDS writes) ----
    const float2* xb2 =
        reinterpret_cast<const float2*>(x + (size_t)b * (CIN * IMG));
#pragma unroll
    for (int i = 0; i < 12; ++i) {
        int f   = tid + i * 1024;        // < 12288 float2s
        int ch  = f / 192;               // 192 float2 per channel (6 rows x 32)
        int rem = f - ch * 192;
        int row = rem >> 5;
        int c2  = rem & 31;
        int gr  = r0 - 1 + row;
        float2 val = make_float2(0.f, 0.f);
        if ((unsigned)gr < (unsigned)H_)
            val = xb2[((ch << 6) | gr) * 32 + c2];
        *reinterpret_cast<float2*>(&smem[XSB + ch * CHSTR + row * RSTR + c2 * 2]) = val;
    }
    // ---- zero pads: 2 guard floats + 2 per (ch,row) ----
    if (tid < 770) {
        int idx = (tid < 768) ? (XSB + (tid >> 1) * RSTR + 64 + (tid & 1))
                              : (tid - 768);
        smem[idx] = 0.0f;
    }
    __syncthreads();

    const int wave = tid >> 6;
    const int lane = tid & 63;
    const size_t obase0 =
        (((size_t)b * OCH) * PH + (strip << 1) + (lane & 1)) * PW + (lane >> 1);

#pragma unroll 1
    for (int q = 0; q < 8; ++q) {
        const int oc = __builtin_amdgcn_readfirstlane(wave * 8 + q);
        const int* D = ((const int*)ws) + DESC_OFF + oc * NLEAF;

        // leaf bases first, then issue all LDS loads; coeff s_loads overlap
        int base[NLEAF];
#pragma unroll
        for (int n = 0; n < NLEAF; ++n)
            base[n] = D[n] + lane;               // desc is SGPR (s_load)

        f2 lo[NLEAF], hi[NLEAF];                 // rows (r0,r0+1), (r0+2,r0+3)
#pragma unroll
        for (int n = 0; n < NLEAF; ++n) {
            lo[n].x = smem[base[n]];
            lo[n].y = smem[base[n] + RSTR];      // ds_read2_b32 0/66
            hi[n].x = smem[base[n] + 2 * RSTR];
            hi[n].y = smem[base[n] + 3 * RSTR];  // ds_read2_b32 132/198
        }

        const float4* C4 = reinterpret_cast<const float4*>(ws) + oc * C_STRIDE_F4;

        // 15-gate polynomial tree, two packed row-pairs
        int go = 0;
#pragma unroll
        for (int lev = 8; lev >= 1; lev >>= 1) {
#pragma unroll
            for (int t = 0; t < lev; ++t) {
                const float4 cc = C4[go + t];    // uniform s_load
                f2 al = lo[2 * t], bl = lo[2 * t + 1];
                f2 ah = hi[2 * t], bh = hi[2 * t + 1];
                f2 ml = al * bl;
                f2 mh = ah * bh;
                f2 rl = al * cc.y;
                f2 rh = ah * cc.y;
                rl += bl * cc.z;
                rh += bh * cc.z;
                rl += ml * cc.w;
                rh += mh * cc.w;
                rl += cc.x;
                rh += cc.x;
                lo[t] = rl;
                hi[t] = rh;
            }
            go += lev;
        }

        // 2x2 noisy-or pool; even lanes -> pooled row 2*strip, odd -> +1
        float p0 = (1.0f - lo[0].x) * (1.0f - lo[0].y);
        float p1 = (1.0f - hi[0].x) * (1.0f - hi[0].y);
        float q0 = p0 * __shfl_xor(p0, 1, 64);
        float q1 = p1 * __shfl_xor(p1, 1, 64);
        float val = (lane & 1) ? (1.0f - q1) : (1.0f - q0);
        out[obase0 + (size_t)oc * (PH * PW)] = val;
    }
}

extern "C" void kernel_launch(void* const* d_in, const int* in_sizes, int n_in,
                              void* d_out, int out_size, void* d_ws, size_t ws_size,
                              hipStream_t stream) {
    const float* x       = (const float*)d_in[0];
    const float* weights = (const float*)d_in[1];
    const int*   ci      = (const int*)d_in[2];
    const int*   px      = (const int*)d_in[3];
    const int*   py      = (const int*)d_in[4];
    float* out = (float*)d_out;
    float* ws  = (float*)d_ws;   // needs 40 KB

    prep<<<4, 1024, 0, stream>>>(weights, ci, px, py, ws);
    logic_tree_main<<<BATCH * 16, 1024, 0, stream>>>(x, ws, out);
}

// Round 10
// 91.964 us; speedup vs baseline: 1.0118x; 1.0118x over previous
//
#include <hip/hip_runtime.h>

// Problem constants
#define BATCH 16
#define CIN   64
#define H_    64
#define W_    64
#define IMG   (H_ * W_)      // 4096
#define OCH   128
#define NLEAF 16
#define NGATE 15
#define PH    32
#define PW    32

// LDS layout (floats). Total 27908 floats = 111,632 B (< 128 KB graph-safe
// limit; 140 KB in R9 broke graph replay).
//   [0,1]  guard zeros (desc px-1 underflow target for ch=0,py=0)
//   XS:    [64 ch][6 rows][66 cols], cols 64,65 zero -> free column halos
//          (col -1 of row r aliases row r-1's zero pad; row stride 66)
//   OPS:   128 ocs x 16 op bytes (argmax index per gate; byte 15 pad)
//   DS:    leaf descriptors, 128 x 16 ints: XSB + ch*396 + py*66 + px - 1
#define ROWS   6
#define RSTR   66
#define CHSTR  (ROWS * RSTR)            // 396
#define XSB    2
#define OPS_F  25348                    // 16B-aligned
#define DS_F   (OPS_F + OCH * 4)        // 25860 (int units == float units)
#define SMEM_F (DS_F + OCH * NLEAF)     // 27908 floats

typedef float f4v __attribute__((ext_vector_type(4)));

__device__ __constant__ __align__(16) float OP2POLY[16][4] = {
    {0, 0, 0, 0}, {0, 0, 0, 1}, {0, 1, 0, -1}, {0, 1, 0, 0},
    {0, 0, 1, -1}, {0, 0, 1, 0}, {0, 1, 1, -2}, {0, 1, 1, -1},
    {1, -1, -1, 1}, {1, -1, -1, 2}, {1, 0, -1, 0}, {1, 0, -1, 1},
    {1, -1, 0, 0}, {1, -1, 0, 1}, {1, 0, 0, -1}, {1, 0, 0, 0}};

static __device__ __forceinline__ int rfl_i(int v) {
    return __builtin_amdgcn_readfirstlane(v);
}

// ---------------------------------------------------------------------------
// Single fused kernel. Block = (b, strip of 4 pre-pool rows); 1024 threads =
// 16 waves; XCD swizzle (XCD x -> batches 2x,2x+1). Phase 1: stage x rows
// r0-1..r0+4 (64 ch) into stride-66 LDS with zeroed pads (free halos);
// redundantly compute per-gate argmax op bytes (forward value of the
// straight-through w is exactly the one-hot argmax) and leaf descriptors
// into LDS. Phase 2: wave w -> ocs [8w,8w+8); lane = column. Per oc: op
// bytes via one broadcast ds_read_b128 -> readfirstlane -> scalar OP2POLY
// lookup (s_load, K$-hot); descs as int4 ds_reads; base = desc + lane; 4
// rows per leaf as f4 (2x ds_read2_b32); 15-gate tree; 2x2 noisy-or pool;
// one all-lane store.
// ---------------------------------------------------------------------------
__global__ __launch_bounds__(1024, 4) void logic_tree_fused(
    const float* __restrict__ x,        // (B, Cin, 64, 64)
    const float* __restrict__ weights,  // (OC, 15, 16)
    const int* __restrict__ ci,         // (OC, 16)
    const int* __restrict__ px,         // (OC, 16)
    const int* __restrict__ py,         // (OC, 16)
    float* __restrict__ out)            // (B, OC, 32, 32)
{
    __shared__ float smem[SMEM_F];
    int* smem_i = (int*)smem;
    unsigned char* smem_b = (unsigned char*)smem;

    const int blk = blockIdx.x;
    const int xcd = blk & 7;
    const int j   = blk >> 3;
    const int b   = (xcd << 1) | (j >> 4);
    const int strip = j & 15;
    const int r0  = strip << 2;
    const int tid = threadIdx.x;

    // ---- stage x interior (float2 loads) ----
    const float2* xb2 =
        reinterpret_cast<const float2*>(x + (size_t)b * (CIN * IMG));
#pragma unroll
    for (int i = 0; i < 12; ++i) {
        int f   = tid + i * 1024;        // < 12288 float2s
        int ch  = f / 192;               // 192 float2 per channel (6 rows x 32)
        int rem = f - ch * 192;
        int row = rem >> 5;
        int c2  = rem & 31;
        int gr  = r0 - 1 + row;
        float2 val = make_float2(0.f, 0.f);
        if ((unsigned)gr < (unsigned)H_)
            val = xb2[((ch << 6) | gr) * 32 + c2];
        *reinterpret_cast<float2*>(&smem[XSB + ch * CHSTR + row * RSTR + c2 * 2]) = val;
    }
    // ---- zero pads: cols 64,65 of each (ch,row) + 2 guard floats ----
    if (tid < 770) {
        int idx = (tid < 768) ? (XSB + (tid >> 1) * RSTR + 64 + (tid & 1))
                              : (tid - 768);
        smem[idx] = 0.0f;
    }
    // ---- per-gate argmax -> op byte in LDS (byte 15 of each oc zeroed) ----
    for (int t = tid; t < OCH * NGATE; t += 1024) {
        const float4* wp4 = reinterpret_cast<const float4*>(weights + t * 16);
        const float4 a0 = wp4[0], a1 = wp4[1], a2 = wp4[2], a3 = wp4[3];
        const float wv[16] = {a0.x, a0.y, a0.z, a0.w, a1.x, a1.y, a1.z, a1.w,
                              a2.x, a2.y, a2.z, a2.w, a3.x, a3.y, a3.z, a3.w};
        int best = 0;
        float bv = wv[0];
#pragma unroll
        for (int k = 1; k < 16; ++k)
            if (wv[k] > bv) { bv = wv[k]; best = k; }   // first-max (jnp.argmax)
        int oc = t / 15, g = t - oc * 15;
        smem_b[OPS_F * 4 + oc * 16 + g] = (unsigned char)best;
        if (g == 14) smem_b[OPS_F * 4 + oc * 16 + 15] = 0;
    }
    // ---- leaf descriptors ----
    for (int t = tid; t < OCH * NLEAF; t += 1024)
        smem_i[DS_F + t] = XSB + ci[t] * CHSTR + py[t] * RSTR + px[t] - 1;
    __syncthreads();

    const int wave = tid >> 6;
    const int lane = tid & 63;
    const size_t obase0 =
        (((size_t)b * OCH) * PH + (strip << 1) + (lane & 1)) * PW + (lane >> 1);

#pragma unroll 1
    for (int q = 0; q < 8; ++q) {
        const int oc = wave * 8 + q;

        // op bytes: one broadcast ds_read_b128 -> SGPRs
        const uint4 opsv = *reinterpret_cast<const uint4*>(&smem[OPS_F + oc * 4]);
        const unsigned ou[4] = {
            (unsigned)rfl_i((int)opsv.x), (unsigned)rfl_i((int)opsv.y),
            (unsigned)rfl_i((int)opsv.z), (unsigned)rfl_i((int)opsv.w)};

        // leaf descriptors (contiguous -> int4 LDS loads), base = desc + lane
        int base[NLEAF];
        const int4* D4 = reinterpret_cast<const int4*>(smem_i + DS_F + oc * NLEAF);
#pragma unroll
        for (int m = 0; m < 4; ++m) {
            const int4 d = D4[m];
            base[4 * m + 0] = d.x + lane;
            base[4 * m + 1] = d.y + lane;
            base[4 * m + 2] = d.z + lane;
            base[4 * m + 3] = d.w + lane;
        }

        // rows r0..r0+3 per leaf as one f4 (two ds_read2_b32: 0/66, 132/198)
        f4v v[NLEAF];
#pragma unroll
        for (int n = 0; n < NLEAF; ++n) {
            v[n].x = smem[base[n]];
            v[n].y = smem[base[n] + RSTR];
            v[n].z = smem[base[n] + 2 * RSTR];
            v[n].w = smem[base[n] + 3 * RSTR];
        }

        // 15-gate polynomial tree, 4 rows wide; coeffs via scalar OP2POLY
        int go = 0;
#pragma unroll
        for (int lev = 8; lev >= 1; lev >>= 1) {
#pragma unroll
            for (int t = 0; t < lev; ++t) {
                const int g  = go + t;
                const int op = (int)((ou[g >> 2] >> ((g & 3) * 8)) & 255u);
                const float4 cc = reinterpret_cast<const float4*>(OP2POLY)[op];
                f4v a  = v[2 * t];
                f4v bb = v[2 * t + 1];
                v[t] = cc.x + cc.y * a + cc.z * bb + cc.w * (a * bb);
            }
            go += lev;
        }

        // 2x2 noisy-or pool; even lanes -> pooled row 2*strip, odd -> +1
        float p0 = (1.0f - v[0].x) * (1.0f - v[0].y);
        float p1 = (1.0f - v[0].z) * (1.0f - v[0].w);
        float q0 = p0 * __shfl_xor(p0, 1, 64);
        float q1 = p1 * __shfl_xor(p1, 1, 64);
        float val = (lane & 1) ? (1.0f - q1) : (1.0f - q0);
        out[obase0 + (size_t)oc * (PH * PW)] = val;
    }
}

extern "C" void kernel_launch(void* const* d_in, const int* in_sizes, int n_in,
                              void* d_out, int out_size, void* d_ws, size_t ws_size,
                              hipStream_t stream) {
    const float* x       = (const float*)d_in[0];
    const float* weights = (const float*)d_in[1];
    const int*   ci      = (const int*)d_in[2];
    const int*   px      = (const int*)d_in[3];
    const int*   py      = (const int*)d_in[4];
    float* out = (float*)d_out;
    (void)d_ws; (void)ws_size;

    logic_tree_fused<<<BATCH * 16, 1024, 0, stream>>>(x, weights, ci, px, py, out);
}